// Round 10
// baseline (1040.851 us; speedup 1.0000x reference)
//
#include <hip/hip_runtime.h>
#include <hip/hip_bf16.h>
#include <hip/hip_cooperative_groups.h>

namespace cg = cooperative_groups;

// ---------------------------------------------------------------------------
// GraphSAGE 3-layer, bf16, bucket-CSR — ONE cooperative kernel.
// R10 vs R9: (1) revert R9's cast/scatter interleave (regressed: both phases
// contend for the same memory pipe; m114 overlap needs *different* pipes) and
// revert dual-node agg (unattributable). (2) Collapse all 9 dispatches into a
// single hipLaunchCooperativeKernel with grid.sync() between stages — budget
// arithmetic shows ~120-180us of the 393us wall is dispatch-boundary dead
// time (~13-20us x 9). Fallback to discrete launches if coop launch errors.
// ---------------------------------------------------------------------------

typedef __attribute__((ext_vector_type(8))) short bf16x8;
typedef __attribute__((ext_vector_type(4))) float floatx4;

constexpr int M0 = 50000, M1 = 25000, M2 = 12500;
constexpr int NODE_OFF1 = 50000, NODE_OFF2 = 75000, M_TOT = 87500;
constexpr int NSRC = 100000;
constexpr int NPART = 8;
constexpr int CAP = 64;
constexpr int PK = 72;                  // LDS row pitch (bf16)
constexpr int CAST_B = 25000;           // NSRC*256/4 / 256
constexpr int PREP_B = 640;

struct SageArgs {
    const float* x;
    const float *Wn0, *Ws0, *Wn1, *Ws1, *Wn2, *Ws2;
    const float *b0, *b1, *b2;
    const int *src0, *dst0, *src1, *dst1, *src2, *dst2;
    int E0, E1, E2, SC_B;
    unsigned short *xb, *mean, *h0, *h1, *Wt0, *Wt1, *Wt2;
    int *wptr, *bkt;
    float* out;
};

__device__ inline unsigned short f2bf(float f) {
    union { float f; unsigned int u; } v{f};
    unsigned int u = v.u;
    return (unsigned short)((u + 0x7FFFu + ((u >> 16) & 1u)) >> 16);  // RNE
}
__device__ inline float bf2f(unsigned short h) {
    union { unsigned int u; float f; } v{(unsigned int)h << 16};
    return v.f;
}

// ---- stage: zero wptr -----------------------------------------------------
__device__ __forceinline__ void stage_zero(const SageArgs& a, int nb)
{
    for (int i = blockIdx.x * 256 + threadIdx.x; i < M_TOT; i += nb * 256)
        a.wptr[i] = 0;
}

// ---- stage: cast | prep | scatter (sequential roles, grid-stride) ---------
__device__ __forceinline__ void stage_front(const SageArgs& a, int nb)
{
    const int E0 = a.E0, E1 = a.E1, E2 = a.E2;
    const int units = CAST_B + PREP_B + a.SC_B;
    for (int u = blockIdx.x; u < units; u += nb) {
        if (u < CAST_B) {
            long i = (long)u * 256 + threadIdx.x;
            float4 v = reinterpret_cast<const float4*>(a.x)[i];
            ushort4 o{f2bf(v.x), f2bf(v.y), f2bf(v.z), f2bf(v.w)};
            reinterpret_cast<ushort4*>(a.xb)[i] = o;
        } else if (u < CAST_B + PREP_B) {
            int b = u - CAST_B;
            const float* Wn; const float* Ws; unsigned short* Wt; int N; int base;
            if (b < 256)      { Wn = a.Wn0; Ws = a.Ws0; Wt = a.Wt0; N = 256; base = 0; }
            else if (b < 512) { Wn = a.Wn1; Ws = a.Ws1; Wt = a.Wt1; N = 256; base = 256; }
            else              { Wn = a.Wn2; Ws = a.Ws2; Wt = a.Wt2; N = 128; base = 512; }
            int idx = (b - base) * 256 + threadIdx.x;
            int n = idx >> 8, k = idx & 255;
            if (n < N) {
                Wt[(size_t)n * 512 + k]       = f2bf(Wn[(size_t)k * N + n]);
                Wt[(size_t)n * 512 + 256 + k] = f2bf(Ws[(size_t)k * N + n]);
            }
        } else {
            // node-partitioned bucket scatter (R6-proven store-locality trick)
            const int b = u - CAST_B - PREP_B;
            const int part = b & (NPART - 1);
            const int i = (b >> 3) * 256 + threadIdx.x;
            const int lo = (int)(((long)M_TOT * part) / NPART);
            const int hi = (int)(((long)M_TOT * (part + 1)) / NPART);
            int node = -1, s = 0;
            if (i < E0) {
                node = a.dst0[i]; s = a.src0[i];
            } else if (i < E0 + E1) {
                int j = i - E0; node = NODE_OFF1 + a.dst1[j]; s = a.src1[j];
            } else if (i < E0 + E1 + E2) {
                int j = i - E0 - E1; node = NODE_OFF2 + a.dst2[j]; s = a.src2[j];
            }
            if (node >= lo && node < hi) {
                int p = atomicAdd(&a.wptr[node], 1);
                if (p < CAP) a.bkt[(size_t)node * CAP + p] = s;
            }
        }
    }
}

// ---- stage: gather-mean (1 wave/node, full index list preloaded) ----------
__device__ __forceinline__ void stage_agg(
    const unsigned short* __restrict__ h, const int* __restrict__ wp,
    const int* __restrict__ bk, unsigned short* __restrict__ mean,
    int M, int nb)
{
    const int lane = threadIdx.x & 63;
    const int wid = threadIdx.x >> 6;
    for (int node = blockIdx.x * 4 + wid; node < M; node += nb * 4) {
        int cnt = min(wp[node], CAP);
        int sidx = bk[(size_t)node * CAP + lane];   // whole list, 1 coalesced read
        float ax = 0.f, ay = 0.f, az = 0.f, aw = 0.f;
        int e = 0;
        for (; e + 8 <= cnt; e += 8) {
#pragma unroll
            for (int j = 0; j < 8; ++j) {
                int s = __shfl(sidx, e + j);
                ushort4 v = *(const ushort4*)(h + (size_t)s * 256 + lane * 4);
                ax += bf2f(v.x); ay += bf2f(v.y); az += bf2f(v.z); aw += bf2f(v.w);
            }
        }
        for (; e < cnt; ++e) {
            int s = __shfl(sidx, e);
            ushort4 v = *(const ushort4*)(h + (size_t)s * 256 + lane * 4);
            ax += bf2f(v.x); ay += bf2f(v.y); az += bf2f(v.z); aw += bf2f(v.w);
        }
        float invd = 1.0f / (float)max(cnt, 1);
        ushort4 o{f2bf(ax * invd), f2bf(ay * invd), f2bf(az * invd), f2bf(aw * invd)};
        *(ushort4*)(mean + (size_t)node * 256 + lane * 4) = o;
    }
}

// ---- stage: fused-K MFMA GEMM over grid-strided 128x128 tiles -------------
template <int RELU, int OUT_BF16>
__device__ __forceinline__ void stage_gemm(
    unsigned short (*sA)[PK], unsigned short (*sB)[PK],
    const unsigned short* __restrict__ A1, const unsigned short* __restrict__ A2,
    const unsigned short* __restrict__ Wt, const float* __restrict__ bias,
    void* __restrict__ out, int M, int N, int nb)
{
    const int tid = threadIdx.x;
    const int tiles_m = (M + 127) >> 7;
    const int tiles_n = N >> 7;
    const int tiles = tiles_m * tiles_n;
    const int wid = tid >> 6, lane = tid & 63;
    const int wm = (wid >> 1) * 64;
    const int wn = (wid & 1) * 64;
    const int quad = lane >> 4, l16 = lane & 15;
    const int sr = tid >> 1;
    const int sc = (tid & 1) * 32;

    for (int t = blockIdx.x; t < tiles; t += nb) {
        const int bm = (t / tiles_n) * 128;
        const int bn = (t % tiles_n) * 128;
        floatx4 acc[4][4] = {};

        for (int k0 = 0; k0 < 512; k0 += 64) {
            const unsigned short* Ab = (k0 < 256) ? A1 : A2;
            const int ak = k0 & 255;
            const float4* ag = (const float4*)(Ab + (size_t)(bm + sr) * 256 + ak + sc);
            float4 a0 = ag[0], a1 = ag[1], a2 = ag[2], a3 = ag[3];
            const float4* bg = (const float4*)(Wt + (size_t)(bn + sr) * 512 + k0 + sc);
            float4 b0 = bg[0], b1 = bg[1], b2 = bg[2], b3 = bg[3];
            __syncthreads();
            *(float4*)&sA[sr][sc]      = a0;
            *(float4*)&sA[sr][sc + 8]  = a1;
            *(float4*)&sA[sr][sc + 16] = a2;
            *(float4*)&sA[sr][sc + 24] = a3;
            *(float4*)&sB[sr][sc]      = b0;
            *(float4*)&sB[sr][sc + 8]  = b1;
            *(float4*)&sB[sr][sc + 16] = b2;
            *(float4*)&sB[sr][sc + 24] = b3;
            __syncthreads();
#pragma unroll
            for (int ks = 0; ks < 64; ks += 32) {
                bf16x8 af[4], bfr[4];
#pragma unroll
                for (int i = 0; i < 4; ++i)
                    af[i] = *(const bf16x8*)&sA[wm + i * 16 + l16][ks + quad * 8];
#pragma unroll
                for (int j = 0; j < 4; ++j)
                    bfr[j] = *(const bf16x8*)&sB[wn + j * 16 + l16][ks + quad * 8];
#pragma unroll
                for (int i = 0; i < 4; ++i)
#pragma unroll
                    for (int j = 0; j < 4; ++j)
                        acc[i][j] = __builtin_amdgcn_mfma_f32_16x16x32_bf16(
                            af[i], bfr[j], acc[i][j], 0, 0, 0);
            }
        }

        // epilogue: C row = quad*4 + reg, col = l16 (verified m89/m91)
#pragma unroll
        for (int j = 0; j < 4; ++j) {
            int col = bn + wn + j * 16 + l16;
            float bcol = bias[col];
#pragma unroll
            for (int i = 0; i < 4; ++i) {
#pragma unroll
                for (int r = 0; r < 4; ++r) {
                    int row = bm + wm + i * 16 + quad * 4 + r;
                    if (row < M) {
                        float v = acc[i][j][r] + bcol;
                        if (RELU) v = fmaxf(v, 0.0f);
                        if (OUT_BF16)
                            ((unsigned short*)out)[(size_t)row * N + col] = f2bf(v);
                        else
                            ((float*)out)[(size_t)row * N + col] = v;
                    }
                }
            }
        }
    }
}

// ---- the cooperative mega-kernel ------------------------------------------

__global__ __launch_bounds__(256, 3) void sage_all(SageArgs a)
{
    __shared__ unsigned short sA[128][PK];
    __shared__ unsigned short sB[128][PK];
    cg::grid_group grid = cg::this_grid();
    const int nb = gridDim.x;

    stage_zero(a, nb);
    __threadfence(); grid.sync();

    stage_front(a, nb);
    __threadfence(); grid.sync();

    stage_agg(a.xb, a.wptr, a.bkt, a.mean, M0, nb);
    __threadfence(); grid.sync();
    stage_gemm<1, 1>(sA, sB, a.mean, a.xb, a.Wt0, a.b0, a.h0, M0, 256, nb);
    __threadfence(); grid.sync();

    stage_agg(a.h0, a.wptr + NODE_OFF1, a.bkt + (size_t)NODE_OFF1 * CAP, a.mean, M1, nb);
    __threadfence(); grid.sync();
    stage_gemm<1, 1>(sA, sB, a.mean, a.h0, a.Wt1, a.b1, a.h1, M1, 256, nb);
    __threadfence(); grid.sync();

    stage_agg(a.h1, a.wptr + NODE_OFF2, a.bkt + (size_t)NODE_OFF2 * CAP, a.mean, M2, nb);
    __threadfence(); grid.sync();
    stage_gemm<0, 0>(sA, sB, a.mean, a.h1, a.Wt2, a.b2, a.out, M2, 128, nb);
}

// ---- discrete-launch fallback (same device code) --------------------------

__global__ __launch_bounds__(256) void k_zero(SageArgs a) { stage_zero(a, gridDim.x); }
__global__ __launch_bounds__(256) void k_front(SageArgs a) { stage_front(a, gridDim.x); }
__global__ __launch_bounds__(256) void k_agg(SageArgs a, int layer)
{
    if (layer == 0)      stage_agg(a.xb, a.wptr, a.bkt, a.mean, M0, gridDim.x);
    else if (layer == 1) stage_agg(a.h0, a.wptr + NODE_OFF1,
                                   a.bkt + (size_t)NODE_OFF1 * CAP, a.mean, M1, gridDim.x);
    else                 stage_agg(a.h1, a.wptr + NODE_OFF2,
                                   a.bkt + (size_t)NODE_OFF2 * CAP, a.mean, M2, gridDim.x);
}
__global__ __launch_bounds__(256) void k_gemm(SageArgs a, int layer)
{
    __shared__ unsigned short sA[128][PK];
    __shared__ unsigned short sB[128][PK];
    if (layer == 0)      stage_gemm<1, 1>(sA, sB, a.mean, a.xb, a.Wt0, a.b0, a.h0, M0, 256, gridDim.x);
    else if (layer == 1) stage_gemm<1, 1>(sA, sB, a.mean, a.h0, a.Wt1, a.b1, a.h1, M1, 256, gridDim.x);
    else                 stage_gemm<0, 0>(sA, sB, a.mean, a.h1, a.Wt2, a.b2, a.out, M2, 128, gridDim.x);
}

// ---------------------------------------------------------------------------

extern "C" void kernel_launch(void* const* d_in, const int* in_sizes, int n_in,
                              void* d_out, int out_size, void* d_ws, size_t ws_size,
                              hipStream_t stream)
{
    SageArgs a;
    a.x   = (const float*)d_in[0];
    a.Wn0 = (const float*)d_in[1];  a.Ws0 = (const float*)d_in[2];
    a.b0  = (const float*)d_in[3];
    a.Wn1 = (const float*)d_in[4];  a.Ws1 = (const float*)d_in[5];
    a.b1  = (const float*)d_in[6];
    a.Wn2 = (const float*)d_in[7];  a.Ws2 = (const float*)d_in[8];
    a.b2  = (const float*)d_in[9];
    a.src0 = (const int*)d_in[10];  a.dst0 = (const int*)d_in[11];
    a.src1 = (const int*)d_in[12];  a.dst1 = (const int*)d_in[13];
    a.src2 = (const int*)d_in[14];  a.dst2 = (const int*)d_in[15];
    a.E0 = in_sizes[10]; a.E1 = in_sizes[12]; a.E2 = in_sizes[14];
    const int E_tot = a.E0 + a.E1 + a.E2;
    a.SC_B = NPART * ((E_tot + 255) / 256);

    a.xb   = (unsigned short*)d_ws;                 // [100000][256]
    a.mean = a.xb   + (size_t)NSRC  * 256;          // [50048][256]
    a.h0   = a.mean + (size_t)50048 * 256;          // [50048][256]
    a.h1   = a.h0   + (size_t)50048 * 256;          // [25088][256]
    a.Wt0  = a.h1   + (size_t)25088 * 256;          // [256][512]
    a.Wt1  = a.Wt0  + 256 * 512;
    a.Wt2  = a.Wt1  + 256 * 512;                    // [128][512]
    a.wptr = (int*)(a.Wt2 + 128 * 512);             // [87500]
    a.bkt  = a.wptr + M_TOT;                        // [87500*64]
    a.out  = (float*)d_out;

    // grid = co-resident capacity (cooperative requirement), capped at 768
    int maxb = 0;
    hipError_t oe = hipOccupancyMaxActiveBlocksPerMultiprocessor(
        &maxb, (const void*)sage_all, 256, 0);
    int grid = (oe == hipSuccess && maxb > 0) ? maxb * 256 : 256;
    if (grid > 768) grid = 768;

    void* kargs[] = { (void*)&a };
    hipError_t err = hipLaunchCooperativeKernel(
        (const void*)sage_all, dim3(grid), dim3(256), kargs, 0, stream);

    if (err != hipSuccess) {
        // fallback: discrete launches of the same stage code
        k_zero<<<dim3(88), dim3(256), 0, stream>>>(a);
        k_front<<<dim3(CAST_B + PREP_B + a.SC_B), dim3(256), 0, stream>>>(a);
        for (int l = 0; l < 3; ++l) {
            int M = (l == 0) ? M0 : (l == 1) ? M1 : M2;
            int N = (l == 2) ? 128 : 256;
            k_agg<<<dim3((M + 3) / 4), dim3(256), 0, stream>>>(a, l);
            int tiles = ((M + 127) / 128) * (N / 128);
            k_gemm<<<dim3(tiles), dim3(256), 0, stream>>>(a, l);
        }
    }
}

// Round 11
// 380.401 us; speedup vs baseline: 2.7362x; 2.7362x over previous
//
#include <hip/hip_runtime.h>
#include <hip/hip_bf16.h>

// ---------------------------------------------------------------------------
// GraphSAGE 3-layer, bf16, bucket-CSR. R11 = R8 structure (best: 393us;
// R10's cooperative mega-kernel regressed 2.6x — grid.sync costs ~100us each
// on ROCm, far more than the ~2us kernel boundary) with two changes:
//   (1) aggregation: 16B/lane gathers — 32 lanes per 512B row, 2 edge rows
//       per wave-iteration (even/odd halves), shfl_xor(32) combine. Halves
//       the load/shfl/addr instruction count per edge.
//   (2) scatter: src[] read predicated on partition commit (cuts 7/8 of the
//       8x-amplified src reads, ~24MB FETCH).
// ---------------------------------------------------------------------------

typedef __attribute__((ext_vector_type(8))) short bf16x8;
typedef __attribute__((ext_vector_type(8))) unsigned short u16x8;
typedef __attribute__((ext_vector_type(4))) float floatx4;

constexpr int M0 = 50000, M1 = 25000, M2 = 12500;
constexpr int NODE_OFF1 = 50000, NODE_OFF2 = 75000, M_TOT = 87500;
constexpr int NSRC = 100000;
constexpr int NPART = 8;
constexpr int CAP = 64;     // bucket capacity per node

__device__ inline unsigned short f2bf(float f) {
    union { float f; unsigned int u; } v{f};
    unsigned int u = v.u;
    return (unsigned short)((u + 0x7FFFu + ((u >> 16) & 1u)) >> 16);  // RNE
}
__device__ inline float bf2f(unsigned short h) {
    union { unsigned int u; float f; } v{(unsigned int)h << 16};
    return v.f;
}

// ---- fused front-end: x->bf16 cast | weight transpose | bucket scatter ----
// block ranges: [0, CAST_B) cast, [CAST_B, CAST_B+PREP_B) prep, rest scatter.
constexpr int CAST_B = 25000;           // NSRC*256/4 / 256
constexpr int PREP_B = 640;

__global__ __launch_bounds__(256) void front_kernel(
    const float* __restrict__ x, unsigned short* __restrict__ xb,
    const float* __restrict__ Wn0, const float* __restrict__ Ws0,
    const float* __restrict__ Wn1, const float* __restrict__ Ws1,
    const float* __restrict__ Wn2, const float* __restrict__ Ws2,
    unsigned short* __restrict__ Wt0, unsigned short* __restrict__ Wt1,
    unsigned short* __restrict__ Wt2,
    const int* __restrict__ src0, const int* __restrict__ dst0,
    const int* __restrict__ src1, const int* __restrict__ dst1,
    const int* __restrict__ src2, const int* __restrict__ dst2,
    int* __restrict__ wptr, int* __restrict__ bkt,
    int E0, int E1, int E2)
{
    const int blk = blockIdx.x;
    if (blk < CAST_B) {
        long i = (long)blk * 256 + threadIdx.x;     // over NSRC*64 ushort4's
        float4 v = reinterpret_cast<const float4*>(x)[i];
        ushort4 o{f2bf(v.x), f2bf(v.y), f2bf(v.z), f2bf(v.w)};
        reinterpret_cast<ushort4*>(xb)[i] = o;
    } else if (blk < CAST_B + PREP_B) {
        int b = blk - CAST_B;
        const float* Wn; const float* Ws; unsigned short* Wt; int N; int base;
        if (b < 256)      { Wn = Wn0; Ws = Ws0; Wt = Wt0; N = 256; base = 0; }
        else if (b < 512) { Wn = Wn1; Ws = Ws1; Wt = Wt1; N = 256; base = 256; }
        else              { Wn = Wn2; Ws = Ws2; Wt = Wt2; N = 128; base = 512; }
        int idx = (b - base) * 256 + threadIdx.x;   // over N*256, k fastest
        int n = idx >> 8, k = idx & 255;
        if (n >= N) return;
        Wt[(size_t)n * 512 + k]       = f2bf(Wn[(size_t)k * N + n]);
        Wt[(size_t)n * 512 + 256 + k] = f2bf(Ws[(size_t)k * N + n]);
    } else {
        // node-partitioned bucket scatter: b&7 = node partition (contiguous
        // node range -> XCD-local bkt store lines), b>>3 = edge slice.
        // src[] read only on commit (1/8 of lanes).
        const int b = blk - CAST_B - PREP_B;
        const int part = b & (NPART - 1);
        const int i = (b >> 3) * 256 + threadIdx.x;
        const int lo = (int)(((long)M_TOT * part) / NPART);
        const int hi = (int)(((long)M_TOT * (part + 1)) / NPART);
        int node, j;
        const int* sp;
        if (i < E0) {
            node = dst0[i]; sp = src0; j = i;
        } else if (i < E0 + E1) {
            j = i - E0; node = NODE_OFF1 + dst1[j]; sp = src1;
        } else if (i < E0 + E1 + E2) {
            j = i - E0 - E1; node = NODE_OFF2 + dst2[j]; sp = src2;
        } else return;
        if (node >= lo && node < hi) {
            int s = sp[j];
            int p = atomicAdd(&wptr[node], 1);
            if (p < CAP) bkt[(size_t)node * CAP + p] = s;
        }
    }
}

// ---- Aggregation: 1 wave/node, 2 rows per iteration (16B/lane) ------------
// Lanes 0-31 cover even edges' 512B rows, lanes 32-63 odd edges'; element
// group lq = lane&31 covers bf16 elements [lq*8, lq*8+8). shfl_xor(32)
// combines the two partial sums; lanes 0-31 write the 512B mean row.

__global__ __launch_bounds__(256) void aggregate_mean_bf16(
    const unsigned short* __restrict__ h, const int* __restrict__ wptr,
    const int* __restrict__ bkt, unsigned short* __restrict__ mean, int M)
{
    int gid = blockIdx.x * 256 + threadIdx.x;
    int node = gid >> 6;
    int lane = gid & 63;
    if (node >= M) return;
    int cnt = min(wptr[node], CAP);
    int sidx = bkt[(size_t)node * CAP + lane];      // whole list, 1 coalesced read
    const int half = lane >> 5;
    const int lq = lane & 31;
    const unsigned short* hb = h + lq * 8;
    float acc[8] = {};
    int pf = cnt >> 1;          // full pairs: both halves valid, no predication
    int p = 0;
    for (; p + 4 <= pf; p += 4) {
#pragma unroll
        for (int j = 0; j < 4; ++j) {
            int s = __shfl(sidx, 2 * (p + j) + half);
            u16x8 row = *(const u16x8*)(hb + (size_t)s * 256);
#pragma unroll
            for (int k = 0; k < 8; ++k) acc[k] += bf2f(row[k]);
        }
    }
    for (; p < pf; ++p) {
        int s = __shfl(sidx, 2 * p + half);
        u16x8 row = *(const u16x8*)(hb + (size_t)s * 256);
#pragma unroll
        for (int k = 0; k < 8; ++k) acc[k] += bf2f(row[k]);
    }
    if (cnt & 1) {              // odd tail: even half only
        int s = __shfl(sidx, cnt - 1);
        if (half == 0) {
            u16x8 row = *(const u16x8*)(hb + (size_t)s * 256);
#pragma unroll
            for (int k = 0; k < 8; ++k) acc[k] += bf2f(row[k]);
        }
    }
#pragma unroll
    for (int k = 0; k < 8; ++k) acc[k] += __shfl_xor(acc[k], 32);
    if (half == 0) {
        float invd = 1.0f / (float)max(cnt, 1);
        u16x8 o;
#pragma unroll
        for (int k = 0; k < 8; ++k) o[k] = f2bf(acc[k] * invd);
        *(u16x8*)(mean + (size_t)node * 256 + lq * 8) = o;
    }
}

// ---- Fused-K MFMA GEMM ----------------------------------------------------
// C[m][n] = sum_{k<512} Acat[m][k] * Wt[n][k],  Acat = [mean | h] (K-concat).
// 128x128 block tile, BK=64, 4 waves, 64x64/wave as 4x4 mfma_f32_16x16x32_bf16.

template <int RELU, int OUT_BF16>
__global__ __launch_bounds__(256) void sage_mfma(
    const unsigned short* __restrict__ A1,  // mean  [>=ceil128(M)][256]
    const unsigned short* __restrict__ A2,  // hsrc  [>=ceil128(M)][256]
    const unsigned short* __restrict__ Wt,  // [N][512]
    const float* __restrict__ bias,
    void* __restrict__ out, int M, int N)
{
    constexpr int PK = 64 + 8;  // LDS row pitch in bf16 (144 B)
    __shared__ unsigned short sA[128][PK];
    __shared__ unsigned short sB[128][PK];

    const int tid = threadIdx.x;
    const int bm = blockIdx.y * 128;
    const int bn = blockIdx.x * 128;
    const int wid = tid >> 6, lane = tid & 63;
    const int wm = (wid >> 1) * 64;
    const int wn = (wid & 1) * 64;
    const int quad = lane >> 4, l16 = lane & 15;

    const int sr = tid >> 1;
    const int sc = (tid & 1) * 32;

    floatx4 acc[4][4] = {};

    for (int k0 = 0; k0 < 512; k0 += 64) {
        const unsigned short* Ab = (k0 < 256) ? A1 : A2;
        const int ak = k0 & 255;
        const float4* ag = (const float4*)(Ab + (size_t)(bm + sr) * 256 + ak + sc);
        float4 a0 = ag[0], a1 = ag[1], a2 = ag[2], a3 = ag[3];
        const float4* bg = (const float4*)(Wt + (size_t)(bn + sr) * 512 + k0 + sc);
        float4 b0 = bg[0], b1 = bg[1], b2 = bg[2], b3 = bg[3];
        __syncthreads();
        *(float4*)&sA[sr][sc]      = a0;
        *(float4*)&sA[sr][sc + 8]  = a1;
        *(float4*)&sA[sr][sc + 16] = a2;
        *(float4*)&sA[sr][sc + 24] = a3;
        *(float4*)&sB[sr][sc]      = b0;
        *(float4*)&sB[sr][sc + 8]  = b1;
        *(float4*)&sB[sr][sc + 16] = b2;
        *(float4*)&sB[sr][sc + 24] = b3;
        __syncthreads();
#pragma unroll
        for (int ks = 0; ks < 64; ks += 32) {
            bf16x8 af[4], bfr[4];
#pragma unroll
            for (int i = 0; i < 4; ++i)
                af[i] = *(const bf16x8*)&sA[wm + i * 16 + l16][ks + quad * 8];
#pragma unroll
            for (int j = 0; j < 4; ++j)
                bfr[j] = *(const bf16x8*)&sB[wn + j * 16 + l16][ks + quad * 8];
#pragma unroll
            for (int i = 0; i < 4; ++i)
#pragma unroll
                for (int j = 0; j < 4; ++j)
                    acc[i][j] = __builtin_amdgcn_mfma_f32_16x16x32_bf16(
                        af[i], bfr[j], acc[i][j], 0, 0, 0);
        }
    }

    // epilogue: C row = quad*4 + reg, col = l16 (verified m89/m91)
#pragma unroll
    for (int j = 0; j < 4; ++j) {
        int col = bn + wn + j * 16 + l16;
        float bcol = bias[col];
#pragma unroll
        for (int i = 0; i < 4; ++i) {
#pragma unroll
            for (int r = 0; r < 4; ++r) {
                int row = bm + wm + i * 16 + quad * 4 + r;
                if (row < M) {
                    float v = acc[i][j][r] + bcol;
                    if (RELU) v = fmaxf(v, 0.0f);
                    if (OUT_BF16)
                        ((unsigned short*)out)[(size_t)row * N + col] = f2bf(v);
                    else
                        ((float*)out)[(size_t)row * N + col] = v;
                }
            }
        }
    }
}

// ---------------------------------------------------------------------------

extern "C" void kernel_launch(void* const* d_in, const int* in_sizes, int n_in,
                              void* d_out, int out_size, void* d_ws, size_t ws_size,
                              hipStream_t stream)
{
    const float* x   = (const float*)d_in[0];
    const float* Wn0 = (const float*)d_in[1];
    const float* Ws0 = (const float*)d_in[2];
    const float* b0  = (const float*)d_in[3];
    const float* Wn1 = (const float*)d_in[4];
    const float* Ws1 = (const float*)d_in[5];
    const float* b1  = (const float*)d_in[6];
    const float* Wn2 = (const float*)d_in[7];
    const float* Ws2 = (const float*)d_in[8];
    const float* b2  = (const float*)d_in[9];
    const int* src0 = (const int*)d_in[10];
    const int* dst0 = (const int*)d_in[11];
    const int* src1 = (const int*)d_in[12];
    const int* dst1 = (const int*)d_in[13];
    const int* src2 = (const int*)d_in[14];
    const int* dst2 = (const int*)d_in[15];
    const int E0 = in_sizes[10], E1 = in_sizes[12], E2 = in_sizes[14];
    const int E_tot = E0 + E1 + E2;

    // --- workspace layout ---
    unsigned short* xb   = (unsigned short*)d_ws;             // [100000][256]
    unsigned short* mean = xb   + (size_t)NSRC  * 256;        // [50048][256]
    unsigned short* h0   = mean + (size_t)50048 * 256;        // [50048][256]
    unsigned short* h1   = h0   + (size_t)50048 * 256;        // [25088][256]
    unsigned short* Wt0  = h1   + (size_t)25088 * 256;        // [256][512]
    unsigned short* Wt1  = Wt0  + 256 * 512;
    unsigned short* Wt2  = Wt1  + 256 * 512;                  // [128][512]
    int* wptr   = (int*)(Wt2 + 128 * 512);                    // [87500]
    int* bkt    = wptr + M_TOT;                               // [87500*64]
    float* outp = (float*)d_out;

    // wptr must be zero before scatter atomics (stream-ordered).
    hipMemsetAsync(wptr, 0, (size_t)M_TOT * sizeof(int), stream);

    const int sc_b = (E_tot + 255) / 256;
    front_kernel<<<dim3(CAST_B + PREP_B + NPART * sc_b), dim3(256), 0, stream>>>(
        x, xb, Wn0, Ws0, Wn1, Ws1, Wn2, Ws2, Wt0, Wt1, Wt2,
        src0, dst0, src1, dst1, src2, dst2, wptr, bkt, E0, E1, E2);

    auto run_layer = [&](const unsigned short* hin, int node_off, int M,
                         const unsigned short* Wt, const float* b,
                         void* hout, int N, bool relu, bool out_bf16) {
        aggregate_mean_bf16<<<dim3((M + 3) / 4), dim3(256), 0, stream>>>(
            hin, wptr + node_off, bkt + (size_t)node_off * CAP, mean, M);
        dim3 g(N / 128, (M + 127) / 128);
        if (out_bf16)
            sage_mfma<1, 1><<<g, dim3(256), 0, stream>>>(mean, hin, Wt, b, hout, M, N);
        else
            sage_mfma<0, 0><<<g, dim3(256), 0, stream>>>(mean, hin, Wt, b, hout, M, N);
    };

    run_layer(xb, 0,         M0, Wt0, b0, h0,   256, true,  true);
    run_layer(h0, NODE_OFF1, M1, Wt1, b1, h1,   256, true,  true);
    run_layer(h1, NODE_OFF2, M2, Wt2, b2, outp, 128, false, false);
}